// Round 6
// baseline (584.511 us; speedup 1.0000x reference)
//
#include <hip/hip_runtime.h>
#include <hip/hip_bf16.h>
#include <math.h>

// Problem constants
#define L_ 1024
#define B_ 4
#define D_ 1024
#define E_ 8
#define K_ 2
#define H_ 4096
#define T_ (L_*B_)        // 4096 tokens
#define P_ (T_*K_)        // 8192 token-expert pairs
#define PPAD (P_+256)     // padded rows so partial 256-tiles can over-read safely

typedef unsigned short u16;
typedef __attribute__((ext_vector_type(4))) float f32x4;
typedef __attribute__((ext_vector_type(8))) short s16x8;

__device__ __forceinline__ u16 f2bf(float f) {
  uint32_t u = __float_as_uint(f);
  uint32_t r = (u + 0x7FFFu + ((u >> 16) & 1u)) >> 16;  // RNE
  return (u16)r;
}
// gelu tanh-approx in sigmoid form
__device__ __forceinline__ float gelu_fast(float v) {
  float u = v * (1.0f + 0.044715f * v * v);
  float t = __expf(-1.5957691216057308f * u);
  return v / (1.0f + t);
}

// ---------------------------------------------------------------------------
// fp32 [E][R][C] -> bf16 [E][C][R]  (transpose + convert, 64x64 LDS tiles)
// ---------------------------------------------------------------------------
template<int R, int C>
__global__ void convtrans(const float* __restrict__ in, u16* __restrict__ out) {
  __shared__ float tile[64][65];
  int e = blockIdx.z;
  int r0 = blockIdx.y * 64, c0 = blockIdx.x * 64;
  const float* src = in + (size_t)e * R * C;
  u16* dst = out + (size_t)e * R * C;
  int t = threadIdx.x;
  int tr = t >> 4, tc = (t & 15) * 4;
#pragma unroll
  for (int p = 0; p < 4; ++p) {
    int r = tr + p * 16;
    float4 v = *(const float4*)(src + (size_t)(r0 + r) * C + c0 + tc);
    tile[r][tc] = v.x; tile[r][tc+1] = v.y; tile[r][tc+2] = v.z; tile[r][tc+3] = v.w;
  }
  __syncthreads();
#pragma unroll
  for (int p = 0; p < 4; ++p) {
    int c = tr + p * 16;
    ushort4 o;
    o.x = f2bf(tile[tc+0][c]); o.y = f2bf(tile[tc+1][c]);
    o.z = f2bf(tile[tc+2][c]); o.w = f2bf(tile[tc+3][c]);
    *(ushort4*)(dst + (size_t)(c0 + c) * R + r0 + tc) = o;
  }
}

// ---------------------------------------------------------------------------
// Gating: one wave per token. fp32 logits (must match reference top-k).
// ---------------------------------------------------------------------------
__global__ void gating(const float* __restrict__ x, const float* __restrict__ task_param,
                       const float* __restrict__ gw_img, const float* __restrict__ gb_img,
                       const float* __restrict__ gw_txt, const float* __restrict__ gb_txt,
                       const float* __restrict__ tgw, const float* __restrict__ tgb,
                       const float* __restrict__ alpha_p, const int* __restrict__ is_text_p,
                       float4* __restrict__ sel_w, float* __restrict__ prob_part,
                       int* __restrict__ count_part) {
  __shared__ float wprob[4][8];
  __shared__ int wcnt[4][8];
  int wid = threadIdx.x >> 6, lane = threadIdx.x & 63;
  int t = blockIdx.x * 4 + wid;
  int b = t & (B_ - 1);
  int it = is_text_p[0];
  const float* gw = it ? gw_txt : gw_img;
  const float* gb = it ? gb_txt : gb_img;
  float alpha = alpha_p[0];
  const float* xr = x + (size_t)t * D_;
  const float* tp = task_param + (size_t)b * D_;
  float acc[8] = {0,0,0,0,0,0,0,0};
  float tac[8] = {0,0,0,0,0,0,0,0};
  for (int i = 0; i < D_/64; ++i) {
    int d = i * 64 + lane;
    float xv = xr[d], tv = tp[d];
#pragma unroll
    for (int e = 0; e < 8; ++e) {
      acc[e] += xv * gw[d*8 + e];
      tac[e] += tv * tgw[d*8 + e];
    }
  }
#pragma unroll
  for (int e = 0; e < 8; ++e) {
#pragma unroll
    for (int off = 32; off > 0; off >>= 1) {
      acc[e] += __shfl_xor(acc[e], off);
      tac[e] += __shfl_xor(tac[e], off);
    }
  }
  float lg[8];
#pragma unroll
  for (int e = 0; e < 8; ++e)
    lg[e] = (1.0f - alpha) * (acc[e] + gb[e]) + alpha * (tac[e] + tgb[e]);
  float m = lg[0];
#pragma unroll
  for (int e = 1; e < 8; ++e) m = fmaxf(m, lg[e]);
  float pr[8], ps = 0.f;
#pragma unroll
  for (int e = 0; e < 8; ++e) { pr[e] = expf(lg[e] - m); ps += pr[e]; }
  float inv = 1.0f / ps;
  int i0 = 0; float v0 = lg[0];
#pragma unroll
  for (int e = 1; e < 8; ++e) if (lg[e] > v0) { v0 = lg[e]; i0 = e; }
  int i1 = -1; float v1 = -1e30f;
#pragma unroll
  for (int e = 0; e < 8; ++e) if (e != i0 && lg[e] > v1) { v1 = lg[e]; i1 = e; }
  float ex = expf(v1 - v0);
  float w0 = 1.0f / (1.0f + ex), w1 = ex / (1.0f + ex);
  if (lane == 0) {
    sel_w[t] = make_float4(__int_as_float(i0), __int_as_float(i1), w0, w1);
#pragma unroll
    for (int e = 0; e < 8; ++e) {
      wprob[wid][e] = pr[e] * inv;
      wcnt[wid][e] = (i0 == e) + (i1 == e);
    }
  }
  __syncthreads();
  if (threadIdx.x < 8) {
    int e = threadIdx.x;
    prob_part[blockIdx.x * 8 + e] = wprob[0][e] + wprob[1][e] + wprob[2][e] + wprob[3][e];
    count_part[blockIdx.x * 8 + e] = wcnt[0][e] + wcnt[1][e] + wcnt[2][e] + wcnt[3][e];
  }
}

// ---------------------------------------------------------------------------
// Finalize: deterministic reduce of partials -> counts/offsets/cursors + l_aux
// ---------------------------------------------------------------------------
__global__ void finalize(const float* __restrict__ prob_part, const int* __restrict__ count_part,
                         int* __restrict__ counts, int* __restrict__ offs,
                         int* __restrict__ cursors, float* __restrict__ laux_out) {
  __shared__ float ps_[256];
  __shared__ int cs_[256];
  int t = threadIdx.x;
  int e = t & 7, s = t >> 3;
  float p = 0.f; int c = 0;
  for (int b = s; b < 1024; b += 32) { p += prob_part[b*8 + e]; c += count_part[b*8 + e]; }
  ps_[t] = p; cs_[t] = c;
  __syncthreads();
  for (int st = 16; st > 0; st >>= 1) {
    if (s < st) { ps_[t] += ps_[t + st*8]; cs_[t] += cs_[t + st*8]; }
    __syncthreads();
  }
  if (t == 0) {
    int off = 0; float laux = 0.f;
    for (int ee = 0; ee < 8; ++ee) {
      int cnt = cs_[ee];
      counts[ee] = cnt; offs[ee] = off; cursors[ee] = off; off += cnt;
      laux += (ps_[ee] * (1.0f/4096.0f)) * ((float)cnt * (1.0f/4096.0f));
    }
    *laux_out = laux;
  }
}

// ---------------------------------------------------------------------------
// Scatter + gather: assign bucket slots, record token->pair map, gather bf16 rows
// ---------------------------------------------------------------------------
__global__ void scatter_gather(const float* __restrict__ x, const float4* __restrict__ sel_w,
                               int* __restrict__ cursors, float* __restrict__ pair_w,
                               int* __restrict__ pair_idx, u16* __restrict__ Xg) {
  int wid = threadIdx.x >> 6, lane = threadIdx.x & 63;
  int t = blockIdx.x * 4 + wid;
  float4 sw = sel_w[t];
  int s0 = __float_as_int(sw.x), s1 = __float_as_int(sw.y);
  int p0 = 0, p1 = 0;
  if (lane == 0) {
    p0 = atomicAdd(&cursors[s0], 1);
    p1 = atomicAdd(&cursors[s1], 1);
  }
  p0 = __shfl(p0, 0); p1 = __shfl(p1, 0);
  if (lane == 0) {
    pair_w[p0] = sw.z; pair_w[p1] = sw.w;
    pair_idx[t*2] = p0; pair_idx[t*2+1] = p1;
  }
  const float* xr = x + (size_t)t * D_;
  u16* d0 = Xg + (size_t)p0 * D_;
  u16* d1 = Xg + (size_t)p1 * D_;
#pragma unroll
  for (int i = 0; i < 4; ++i) {
    int c = i * 256 + lane * 4;
    float4 v = *(const float4*)(xr + c);
    ushort4 o;
    o.x = f2bf(v.x); o.y = f2bf(v.y); o.z = f2bf(v.z); o.w = f2bf(v.w);
    *(ushort4*)(d0 + c) = o;
    *(ushort4*)(d1 + c) = o;
  }
}

// ---------------------------------------------------------------------------
// Grouped GEMM, 256x256 tile, 8 waves (512 thr), K-slice RING pipeline.
//
// Ring: 4 slices of K=32 (16 KB A + 16 KB B each) -> 128 KB LDS, prefetch
// depth 3 slices. Per slice-step:
//   issue stage(s+3) -> slot (s+3)&3  [slot freed at barrier B(s): its last
//     reader was step s-1, whose ds_reads drained via lgkmcnt(0) before B(s)]
//   ds_read slice s (12 x b128) ; lgkmcnt(0)+sched_barrier (rule 18)
//   setprio(1); 32 MFMA; setprio(0)                         (T5)
//   s_waitcnt vmcnt(8)  [FIFO: outstanding {s+1,s+2,s+3}=12 -> retires s+1;
//     slices s+2,s+3 stay in flight ACROSS the barrier]     (T4: never 0)
//   s_barrier           [publishes slice s+1]
// Tail: compute NS-3; vmcnt(0)+barrier (only full drain, once); NS-2; NS-1;
// barrier (protects ring from next bx-iteration's prologue).
//
// LDS swizzle: 4 x 16B slots per row; phys = p ^ (r&3) ^ ((r>>2)&3)
// (involution). Staging LDS dest linear in tid (global_load_lds rule 21);
// global source carries the permutation (quad-contiguous 64B runs).
// Fragment reads: 8 distinct bank-group spread (same profile as R4/R5's
// measured-zero-conflict layout).
//
// Roles: A(m)=weights(features), B(n)=tokens; wf=wid&1 (2x128 feat),
// wt=wid>>1 (4x64 tok); acc[8][4], reg j walks 4 consecutive features.
// KSPLIT (GEMM2): disjoint part buffers summed in combine (deterministic).
// Grid: 1-D, expert = gid&7 (XCD affinity).
// ---------------------------------------------------------------------------
template<int EPI, int KDIM, int KLEN, int NOUT, int NPANEL, int KSPLIT, int JSLOTS>
__global__ __launch_bounds__(512, 2)
void gemm256(const u16* __restrict__ Tok, const u16* __restrict__ Wt,
             const int* __restrict__ counts, const int* __restrict__ offs,
             const float* __restrict__ pair_w,
             u16* __restrict__ Hout, float* __restrict__ Cout) {
  int gid = blockIdx.x;
  int e = gid & 7;
  int idx = gid >> 3;
  int panel = idx % NPANEL; idx /= NPANEL;
  int ks = idx % KSPLIT;    idx /= KSPLIT;
  int j0 = idx;             // [0, JSLOTS)
  int ne = counts[e];
  int off = offs[e];
  int kbase = ks * KLEN;
  float* Cpart = Cout + (size_t)ks * P_ * D_;

  __shared__ u16 As[4][8192];   // 4-slice ring, 256 x 32 bf16 = 16 KB/slice
  __shared__ u16 Bs[4][8192];
  int t = threadIdx.x, lane = t & 63, wid = t >> 6;
  int wf = wid & 1, wt = wid >> 1;

  const u16* Wg = Wt + (size_t)e * NOUT * KDIM + (size_t)panel * 256 * KDIM + kbase;

  // staging map: i covers slots [i*512 + t]; r = slot>>2, p = slot&3,
  // logical kk = p ^ (r&3) ^ ((r>>2)&3)  (inverse of read-side swizzle).
  int goff[2], ldso[2];
#pragma unroll
  for (int i = 0; i < 2; ++i) {
    int slot = i * 512 + t;
    int r = slot >> 2;
    int p = slot & 3;
    int kk = p ^ (r & 3) ^ ((r >> 2) & 3);
    goff[i] = r * KDIM + kk * 8;   // u16 offset from matrix base
    ldso[i] = slot * 8;            // linear u16 LDS offset within slice
  }

  // fragment read offsets (u16): phys slot = p ^ (row&3) ^ ((row>>2)&3)
  int aoff[8], boff[4];
#pragma unroll
  for (int fr = 0; fr < 8; ++fr) {
    int row = wf * 128 + fr * 16 + (lane & 15);
    int p = (lane >> 4) ^ (row & 3) ^ ((row >> 2) & 3);
    aoff[fr] = (row * 4 + p) * 8;
  }
#pragma unroll
  for (int fb = 0; fb < 4; ++fb) {
    int row = wt * 64 + fb * 16 + (lane & 15);
    int p = (lane >> 4) ^ (row & 3) ^ ((row >> 2) & 3);
    boff[fb] = (row * 4 + p) * 8;
  }

  constexpr int NS = KLEN / 32;   // number of K-slices (>= 4)
  int lr = lane & 15, lg4 = (lane >> 4) * 4;

  for (int bx = j0; bx * 256 < ne; bx += JSLOTS) {
    const u16* Tg = Tok + (size_t)(off + bx * 256) * KDIM + kbase;
    f32x4 acc[8][4] = {};

#define STAGE(sl)                                                              \
    {                                                                          \
      int ring_ = (sl) & 3;                                                    \
      int ko_ = (sl) * 32;                                                     \
      _Pragma("unroll")                                                        \
      for (int i_ = 0; i_ < 2; ++i_) {                                         \
        __builtin_amdgcn_global_load_lds(                                      \
            (const __attribute__((address_space(1))) void*)(Wg + goff[i_] + ko_), \
            (__attribute__((address_space(3))) void*)(&As[ring_][ldso[i_]]), 16, 0, 0); \
        __builtin_amdgcn_global_load_lds(                                      \
            (const __attribute__((address_space(1))) void*)(Tg + goff[i_] + ko_), \
            (__attribute__((address_space(3))) void*)(&Bs[ring_][ldso[i_]]), 16, 0, 0); \
      }                                                                        \
    }

#define COMPSL(sl)                                                             \
    {                                                                          \
      const u16* Ab_ = &As[(sl) & 3][0];                                       \
      const u16* Bb_ = &Bs[(sl) & 3][0];                                       \
      s16x8 a_[8], b_[4];                                                      \
      _Pragma("unroll")                                                        \
      for (int r_ = 0; r_ < 8; ++r_) a_[r_] = *(const s16x8*)(Ab_ + aoff[r_]); \
      _Pragma("unroll")                                                        \
      for (int f_ = 0; f_ < 4; ++f_) b_[f_] = *(const s16x8*)(Bb_ + boff[f_]); \
      asm volatile("s_waitcnt lgkmcnt(0)" ::: "memory");                       \
      __builtin_amdgcn_sched_barrier(0);                                       \
      __builtin_amdgcn_s_setprio(1);                                           \
      _Pragma("unroll")                                                        \
      for (int r_ = 0; r_ < 8; ++r_)                                           \
        _Pragma("unroll")                                                      \
        for (int f_ = 0; f_ < 4; ++f_)                                         \
          acc[r_][f_] = __builtin_amdgcn_mfma_f32_16x16x32_bf16(               \
              a_[r_], b_[f_], acc[r_][f_], 0, 0, 0);                           \
      __builtin_amdgcn_s_setprio(0);                                           \
    }

    // prologue: stage slices 0,1,2; publish slice 0
    STAGE(0); STAGE(1); STAGE(2);
    asm volatile("s_waitcnt vmcnt(8)" ::: "memory");
    __builtin_amdgcn_s_barrier();

    int s = 0;
    for (; s + 3 < NS; ++s) {
      STAGE(s + 3);
      COMPSL(s);
      asm volatile("s_waitcnt vmcnt(8)" ::: "memory");
      __builtin_amdgcn_s_barrier();
    }
    // tail: s == NS-3; slices NS-2, NS-1 still possibly in flight
    COMPSL(NS - 3);
    asm volatile("s_waitcnt vmcnt(0)" ::: "memory");
    __builtin_amdgcn_s_barrier();
    COMPSL(NS - 2);
    COMPSL(NS - 1);
    __builtin_amdgcn_s_barrier();   // protect ring before next bx prologue

#undef STAGE
#undef COMPSL

    // epilogue: token = wt*64 + f*16 + lr (col), feature = wf*128 + r*16 + lg4 + j
#pragma unroll
    for (int f = 0; f < 4; ++f) {
      int tokl = bx * 256 + wt * 64 + f * 16 + lr;
      if (tokl >= ne) continue;
      size_t grow = (size_t)(off + tokl);
      if (EPI == 0) {
#pragma unroll
        for (int r = 0; r < 8; ++r) {
          ushort4 o;
          o.x = f2bf(gelu_fast(acc[r][f][0]));
          o.y = f2bf(gelu_fast(acc[r][f][1]));
          o.z = f2bf(gelu_fast(acc[r][f][2]));
          o.w = f2bf(gelu_fast(acc[r][f][3]));
          *(ushort4*)(Hout + grow * NOUT + panel * 256 + wf * 128 + r * 16 + lg4) = o;
        }
      } else {
        float w = pair_w[grow];
#pragma unroll
        for (int r = 0; r < 8; ++r) {
          float4 o;
          o.x = acc[r][f][0] * w; o.y = acc[r][f][1] * w;
          o.z = acc[r][f][2] * w; o.w = acc[r][f][3] * w;
          *(float4*)(Cpart + grow * NOUT + panel * 256 + wf * 128 + r * 16 + lg4) = o;
        }
      }
    }
  }
}

// ---------------------------------------------------------------------------
// Combine: out[token] = sum over 2 pairs x 2 K-parts
// ---------------------------------------------------------------------------
__global__ void combine(const float* __restrict__ pair_out, const int* __restrict__ pair_idx,
                        float* __restrict__ out) {
  const float* part1 = pair_out + (size_t)P_ * D_;
  int t = blockIdx.x;
  int p0 = pair_idx[t*2], p1 = pair_idx[t*2+1];
  int c = threadIdx.x * 4;
  float4 a0 = *(const float4*)(pair_out + (size_t)p0 * D_ + c);
  float4 a1 = *(const float4*)(part1    + (size_t)p0 * D_ + c);
  float4 b0 = *(const float4*)(pair_out + (size_t)p1 * D_ + c);
  float4 b1 = *(const float4*)(part1    + (size_t)p1 * D_ + c);
  float4 o;
  o.x = (a0.x + a1.x) + (b0.x + b1.x);
  o.y = (a0.y + a1.y) + (b0.y + b1.y);
  o.z = (a0.z + a1.z) + (b0.z + b1.z);
  o.w = (a0.w + a1.w) + (b0.w + b1.w);
  *(float4*)(out + (size_t)t * D_ + c) = o;
}

// ---------------------------------------------------------------------------
// Workspace layout (bytes):
//   w1b  [E][H][D] bf16 @ 0           (67108864)  <- aliased by pair_out parts
//   w2b  [E][D][H] bf16 @ 67108864    (67108864)
//   Xg   [PPAD][D] bf16 @ 134217728   (17301504)
//   Hb   [PPAD][H] bf16 @ 151519232   (69206016)
//   small buffers @ 220725248
//   pair_out: 2 parts x [P_][D_] f32 @ 0 (67108864, aliases dead w1b)
// ---------------------------------------------------------------------------
extern "C" void kernel_launch(void* const* d_in, const int* in_sizes, int n_in,
                              void* d_out, int out_size, void* d_ws, size_t ws_size,
                              hipStream_t stream) {
  const float* inputs      = (const float*)d_in[0];
  const float* task_param  = (const float*)d_in[1];
  const float* gate_img_w  = (const float*)d_in[2];
  const float* gate_img_b  = (const float*)d_in[3];
  const float* gate_txt_w  = (const float*)d_in[4];
  const float* gate_txt_b  = (const float*)d_in[5];
  const float* task_gate_w = (const float*)d_in[6];
  const float* task_gate_b = (const float*)d_in[7];
  const float* alpha       = (const float*)d_in[8];
  const float* w1          = (const float*)d_in[9];
  const float* w2          = (const float*)d_in[10];
  const int*   is_text     = (const int*)d_in[11];
  float* out = (float*)d_out;

  char* ws = (char*)d_ws;
  u16* w1b = (u16*)(ws + 0);
  u16* w2b = (u16*)(ws + 67108864);
  u16* Xg  = (u16*)(ws + 134217728);
  u16* Hb  = (u16*)(ws + 151519232);
  float4* sel_w   = (float4*)(ws + 220725248);
  float* pair_w   = (float*)(ws + 220725248 + 65536);
  int* pair_idx   = (int*)(ws + 220725248 + 98816);
  float* prob_part= (float*)(ws + 220725248 + 131584);
  int* count_part = (int*)(ws + 220725248 + 164352);
  int* counters   = (int*)(ws + 220725248 + 197120);
  float* pair_out = (float*)(ws + 0);  // 2 parts, aliases dead w1b

  int* counts  = counters;
  int* offs    = counters + 8;
  int* cursors = counters + 16;

  convtrans<D_, H_><<<dim3(H_/64, D_/64, E_), 256, 0, stream>>>(w1, w1b);
  convtrans<H_, D_><<<dim3(D_/64, H_/64, E_), 256, 0, stream>>>(w2, w2b);
  gating<<<dim3(T_/4), 256, 0, stream>>>(inputs, task_param, gate_img_w, gate_img_b,
      gate_txt_w, gate_txt_b, task_gate_w, task_gate_b, alpha, is_text,
      sel_w, prob_part, count_part);
  finalize<<<dim3(1), 256, 0, stream>>>(prob_part, count_part, counts, offs, cursors,
      out + (size_t)T_ * D_);
  scatter_gather<<<dim3(T_/4), 256, 0, stream>>>(inputs, sel_w, cursors, pair_w, pair_idx, Xg);
  // GEMM1: Tok=Xg, W=w1b; K=1024 (NS=32), 16 panels, 2 token-slots. 256 blocks.
  gemm256<0, D_, D_, H_, 16, 1, 2><<<dim3(256), 512, 0, stream>>>(
      Xg, w1b, counts, offs, pair_w, Hb, (float*)nullptr);
  // GEMM2: Tok=Hb, W=w2b; K=4096 split 2x2048 (NS=64), 4 panels, 4 token-slots. 256 blocks.
  gemm256<1, H_, H_/2, D_, 4, 2, 4><<<dim3(256), 512, 0, stream>>>(
      Hb, w2b, counts, offs, pair_w, (u16*)nullptr, pair_out);
  combine<<<dim3(T_), 256, 0, stream>>>(pair_out, pair_idx, out);
}

// Round 7
// 514.313 us; speedup vs baseline: 1.1365x; 1.1365x over previous
//
#include <hip/hip_runtime.h>
#include <hip/hip_bf16.h>
#include <math.h>

// Problem constants
#define L_ 1024
#define B_ 4
#define D_ 1024
#define E_ 8
#define K_ 2
#define H_ 4096
#define T_ (L_*B_)        // 4096 tokens
#define P_ (T_*K_)        // 8192 token-expert pairs
#define PPAD (P_+256)     // padded rows so partial 256-tiles can over-read safely

typedef unsigned short u16;
typedef __attribute__((ext_vector_type(4))) float f32x4;
typedef __attribute__((ext_vector_type(8))) short s16x8;

__device__ __forceinline__ u16 f2bf(float f) {
  uint32_t u = __float_as_uint(f);
  uint32_t r = (u + 0x7FFFu + ((u >> 16) & 1u)) >> 16;  // RNE
  return (u16)r;
}
// gelu tanh-approx in sigmoid form
__device__ __forceinline__ float gelu_fast(float v) {
  float u = v * (1.0f + 0.044715f * v * v);
  float t = __expf(-1.5957691216057308f * u);
  return v / (1.0f + t);
}

// ---------------------------------------------------------------------------
// fp32 [E][R][C] -> bf16 [E][C][R]  (transpose + convert, 64x64 LDS tiles)
// ---------------------------------------------------------------------------
template<int R, int C>
__global__ void convtrans(const float* __restrict__ in, u16* __restrict__ out) {
  __shared__ float tile[64][65];
  int e = blockIdx.z;
  int r0 = blockIdx.y * 64, c0 = blockIdx.x * 64;
  const float* src = in + (size_t)e * R * C;
  u16* dst = out + (size_t)e * R * C;
  int t = threadIdx.x;
  int tr = t >> 4, tc = (t & 15) * 4;
#pragma unroll
  for (int p = 0; p < 4; ++p) {
    int r = tr + p * 16;
    float4 v = *(const float4*)(src + (size_t)(r0 + r) * C + c0 + tc);
    tile[r][tc] = v.x; tile[r][tc+1] = v.y; tile[r][tc+2] = v.z; tile[r][tc+3] = v.w;
  }
  __syncthreads();
#pragma unroll
  for (int p = 0; p < 4; ++p) {
    int c = tr + p * 16;
    ushort4 o;
    o.x = f2bf(tile[tc+0][c]); o.y = f2bf(tile[tc+1][c]);
    o.z = f2bf(tile[tc+2][c]); o.w = f2bf(tile[tc+3][c]);
    *(ushort4*)(dst + (size_t)(c0 + c) * R + r0 + tc) = o;
  }
}

// ---------------------------------------------------------------------------
// Gating: one wave per token. fp32 logits (must match reference top-k).
// ---------------------------------------------------------------------------
__global__ void gating(const float* __restrict__ x, const float* __restrict__ task_param,
                       const float* __restrict__ gw_img, const float* __restrict__ gb_img,
                       const float* __restrict__ gw_txt, const float* __restrict__ gb_txt,
                       const float* __restrict__ tgw, const float* __restrict__ tgb,
                       const float* __restrict__ alpha_p, const int* __restrict__ is_text_p,
                       float4* __restrict__ sel_w, float* __restrict__ prob_part,
                       int* __restrict__ count_part) {
  __shared__ float wprob[4][8];
  __shared__ int wcnt[4][8];
  int wid = threadIdx.x >> 6, lane = threadIdx.x & 63;
  int t = blockIdx.x * 4 + wid;
  int b = t & (B_ - 1);
  int it = is_text_p[0];
  const float* gw = it ? gw_txt : gw_img;
  const float* gb = it ? gb_txt : gb_img;
  float alpha = alpha_p[0];
  const float* xr = x + (size_t)t * D_;
  const float* tp = task_param + (size_t)b * D_;
  float acc[8] = {0,0,0,0,0,0,0,0};
  float tac[8] = {0,0,0,0,0,0,0,0};
  for (int i = 0; i < D_/64; ++i) {
    int d = i * 64 + lane;
    float xv = xr[d], tv = tp[d];
#pragma unroll
    for (int e = 0; e < 8; ++e) {
      acc[e] += xv * gw[d*8 + e];
      tac[e] += tv * tgw[d*8 + e];
    }
  }
#pragma unroll
  for (int e = 0; e < 8; ++e) {
#pragma unroll
    for (int off = 32; off > 0; off >>= 1) {
      acc[e] += __shfl_xor(acc[e], off);
      tac[e] += __shfl_xor(tac[e], off);
    }
  }
  float lg[8];
#pragma unroll
  for (int e = 0; e < 8; ++e)
    lg[e] = (1.0f - alpha) * (acc[e] + gb[e]) + alpha * (tac[e] + tgb[e]);
  float m = lg[0];
#pragma unroll
  for (int e = 1; e < 8; ++e) m = fmaxf(m, lg[e]);
  float pr[8], ps = 0.f;
#pragma unroll
  for (int e = 0; e < 8; ++e) { pr[e] = expf(lg[e] - m); ps += pr[e]; }
  float inv = 1.0f / ps;
  int i0 = 0; float v0 = lg[0];
#pragma unroll
  for (int e = 1; e < 8; ++e) if (lg[e] > v0) { v0 = lg[e]; i0 = e; }
  int i1 = -1; float v1 = -1e30f;
#pragma unroll
  for (int e = 0; e < 8; ++e) if (e != i0 && lg[e] > v1) { v1 = lg[e]; i1 = e; }
  float ex = expf(v1 - v0);
  float w0 = 1.0f / (1.0f + ex), w1 = ex / (1.0f + ex);
  if (lane == 0) {
    sel_w[t] = make_float4(__int_as_float(i0), __int_as_float(i1), w0, w1);
#pragma unroll
    for (int e = 0; e < 8; ++e) {
      wprob[wid][e] = pr[e] * inv;
      wcnt[wid][e] = (i0 == e) + (i1 == e);
    }
  }
  __syncthreads();
  if (threadIdx.x < 8) {
    int e = threadIdx.x;
    prob_part[blockIdx.x * 8 + e] = wprob[0][e] + wprob[1][e] + wprob[2][e] + wprob[3][e];
    count_part[blockIdx.x * 8 + e] = wcnt[0][e] + wcnt[1][e] + wcnt[2][e] + wcnt[3][e];
  }
}

// ---------------------------------------------------------------------------
// Finalize: deterministic reduce of partials -> counts/offsets/cursors + l_aux
// ---------------------------------------------------------------------------
__global__ void finalize(const float* __restrict__ prob_part, const int* __restrict__ count_part,
                         int* __restrict__ counts, int* __restrict__ offs,
                         int* __restrict__ cursors, float* __restrict__ laux_out) {
  __shared__ float ps_[256];
  __shared__ int cs_[256];
  int t = threadIdx.x;
  int e = t & 7, s = t >> 3;
  float p = 0.f; int c = 0;
  for (int b = s; b < 1024; b += 32) { p += prob_part[b*8 + e]; c += count_part[b*8 + e]; }
  ps_[t] = p; cs_[t] = c;
  __syncthreads();
  for (int st = 16; st > 0; st >>= 1) {
    if (s < st) { ps_[t] += ps_[t + st*8]; cs_[t] += cs_[t + st*8]; }
    __syncthreads();
  }
  if (t == 0) {
    int off = 0; float laux = 0.f;
    for (int ee = 0; ee < 8; ++ee) {
      int cnt = cs_[ee];
      counts[ee] = cnt; offs[ee] = off; cursors[ee] = off; off += cnt;
      laux += (ps_[ee] * (1.0f/4096.0f)) * ((float)cnt * (1.0f/4096.0f));
    }
    *laux_out = laux;
  }
}

// ---------------------------------------------------------------------------
// Scatter + gather: assign bucket slots, record token->pair map, gather bf16 rows
// ---------------------------------------------------------------------------
__global__ void scatter_gather(const float* __restrict__ x, const float4* __restrict__ sel_w,
                               int* __restrict__ cursors, float* __restrict__ pair_w,
                               int* __restrict__ pair_idx, u16* __restrict__ Xg) {
  int wid = threadIdx.x >> 6, lane = threadIdx.x & 63;
  int t = blockIdx.x * 4 + wid;
  float4 sw = sel_w[t];
  int s0 = __float_as_int(sw.x), s1 = __float_as_int(sw.y);
  int p0 = 0, p1 = 0;
  if (lane == 0) {
    p0 = atomicAdd(&cursors[s0], 1);
    p1 = atomicAdd(&cursors[s1], 1);
  }
  p0 = __shfl(p0, 0); p1 = __shfl(p1, 0);
  if (lane == 0) {
    pair_w[p0] = sw.z; pair_w[p1] = sw.w;
    pair_idx[t*2] = p0; pair_idx[t*2+1] = p1;
  }
  const float* xr = x + (size_t)t * D_;
  u16* d0 = Xg + (size_t)p0 * D_;
  u16* d1 = Xg + (size_t)p1 * D_;
#pragma unroll
  for (int i = 0; i < 4; ++i) {
    int c = i * 256 + lane * 4;
    float4 v = *(const float4*)(xr + c);
    ushort4 o;
    o.x = f2bf(v.x); o.y = f2bf(v.y); o.z = f2bf(v.z); o.w = f2bf(v.w);
    *(ushort4*)(d0 + c) = o;
    *(ushort4*)(d1 + c) = o;
  }
}

// ---------------------------------------------------------------------------
// Grouped GEMM, 256x256 tile, BK=64, 8 waves, 8-PHASE schedule (m201 port).
//
// Per iter: 2 K-tiles (buf0=even, buf1=odd), 8 phases. Phase p computes one
// M-pair quadrant (2 M-frags x 4 N-frags x K=64 = 16 MFMA). ph1/ph5 also read
// the tile's 8 B-frags (12 ds_reads); other phases 4 ds_reads.
// Each phase stages 2 x 8KB quarters (1 global_load_lds/thread each) into a
// region whose last reader finished >=1 barrier earlier:
//   ph1: A1q1,A1q3(2j+1)  ph2: B0q0,B0q1(2j+2)  ph3: B0q2,B0q3(2j+2)
//   ph4: A0q0,A0q2(2j+2)  ph5: A0q1,A0q3(2j+2)  ph6: B1q0,B1q1(2j+3)
//   ph7: B1q2,B1q3(2j+3)  ph8: A1q0,A1q2(2j+3)
// Counted waits (FIFO-derived, never 0): vmcnt(10)@ph2, vmcnt(8)@ph4,
// vmcnt(10)@ph6, vmcnt(8)@ph8 — 4-7 quarter-loads stay in flight across
// barriers (2-3.5 K-tiles of latency cover). Prologue: 14 loads + vmcnt(8).
// Tail: tile index clamped to NT-1 (redundant loads keep FIFO intact).
// Epilogue stores age in the same FIFO; next unit's prologue vmcnt(8)
// retires them (stores are older than the 14 prologue loads).
//
// LDS swizzle (R5-verified, 0 conflicts): row = 8 x 16B slots; phys slot =
// kk ^ (row&7); staging dest linear in tid, global source carries inverse.
// Roles: A(m)=weights(features), B(n)=tokens; wf=wid&1, wt=wid>>1; acc[8][4].
// Grid: 1-D, expert = gid&7 (XCD affinity).
// ---------------------------------------------------------------------------
template<int EPI, int KDIM, int KLEN, int NOUT, int NPANEL, int KSPLIT, int JSLOTS>
__global__ __launch_bounds__(512, 2)
void gemm256(const u16* __restrict__ Tok, const u16* __restrict__ Wt,
             const int* __restrict__ counts, const int* __restrict__ offs,
             const float* __restrict__ pair_w,
             u16* __restrict__ Hout, float* __restrict__ Cout) {
  int gid = blockIdx.x;
  int e = gid & 7;
  int idx = gid >> 3;
  int panel = idx % NPANEL; idx /= NPANEL;
  int ks = idx % KSPLIT;    idx /= KSPLIT;
  int j0 = idx;             // [0, JSLOTS)
  int ne = counts[e];
  int off = offs[e];
  int kbase = ks * KLEN;
  float* Cpart = Cout + (size_t)ks * P_ * D_;

  __shared__ u16 As[2][16384];   // 256 x 64 bf16 = 32 KB per buffer
  __shared__ u16 Bs[2][16384];
  int t = threadIdx.x, lane = t & 63, wid = t >> 6;
  int wf = wid & 1, wt = wid >> 1;

  const u16* Wg = Wt + (size_t)e * NOUT * KDIM + (size_t)panel * 256 * KDIM + kbase;

  // staging map (quarter q): slot = q*512 + t; row = slot>>3,
  // kk = (slot&7) ^ (row&7); 1 load/thread per 8KB quarter.
  int goff[4]; int ldso[4];
#pragma unroll
  for (int i = 0; i < 4; ++i) {
    int slot = i * 512 + t;
    int row = slot >> 3;
    int kk = (slot & 7) ^ (row & 7);
    goff[i] = row * KDIM + kk * 8;
    ldso[i] = slot * 8;
  }

  // fragment read offsets (u16): phys = (row*8 + (kk ^ (row&7)))*8
  int aoff[8][2], boff[4][2];
#pragma unroll
  for (int r = 0; r < 8; ++r) {
    int row = wf * 128 + r * 16 + (lane & 15);
#pragma unroll
    for (int h = 0; h < 2; ++h) {
      int kk = h * 4 + (lane >> 4);
      aoff[r][h] = (row * 8 + (kk ^ (row & 7))) * 8;
    }
  }
#pragma unroll
  for (int f = 0; f < 4; ++f) {
    int row = wt * 64 + f * 16 + (lane & 15);
#pragma unroll
    for (int h = 0; h < 2; ++h) {
      int kk = h * 4 + (lane >> 4);
      boff[f][h] = (row * 8 + (kk ^ (row & 7))) * 8;
    }
  }

  constexpr int NT = KLEN / 64;       // K-tiles per unit (16 or 32)
  constexpr int NITER = NT / 2;
  int lr = lane & 15, lg4 = (lane >> 4) * 4;

#define STA(b, q, tk) __builtin_amdgcn_global_load_lds( \
      (const __attribute__((address_space(1))) void*)(Wg + goff[q] + (tk) * 64), \
      (__attribute__((address_space(3))) void*)(&As[b][ldso[q]]), 16, 0, 0)
#define STB(b, q, tk) __builtin_amdgcn_global_load_lds( \
      (const __attribute__((address_space(1))) void*)(Tg + goff[q] + (tk) * 64), \
      (__attribute__((address_space(3))) void*)(&Bs[b][ldso[q]]), 16, 0, 0)

// One phase: M-pair MP from buffer TB; DOB=reload B-frags; stages via
// __VA_ARGS__; VM in {0(none),8,10}; LG8: issue lgkmcnt(8) pre-barrier.
#define PH(MP, TB, DOB, VM, LG8, ...)                                          \
  {                                                                            \
    s16x8 a00 = *(const s16x8*)(&As[TB][aoff[(MP)*2+0][0]]);                   \
    s16x8 a01 = *(const s16x8*)(&As[TB][aoff[(MP)*2+0][1]]);                   \
    s16x8 a10 = *(const s16x8*)(&As[TB][aoff[(MP)*2+1][0]]);                   \
    s16x8 a11 = *(const s16x8*)(&As[TB][aoff[(MP)*2+1][1]]);                   \
    if (DOB) {                                                                 \
      _Pragma("unroll")                                                        \
      for (int nf = 0; nf < 4; ++nf) {                                         \
        bn[nf][0] = *(const s16x8*)(&Bs[TB][boff[nf][0]]);                     \
        bn[nf][1] = *(const s16x8*)(&Bs[TB][boff[nf][1]]);                     \
      }                                                                        \
    }                                                                          \
    __VA_ARGS__;                                                               \
    if (LG8) asm volatile("s_waitcnt lgkmcnt(8)" ::: "memory");                \
    __builtin_amdgcn_s_barrier();                                              \
    asm volatile("s_waitcnt lgkmcnt(0)" ::: "memory");                         \
    __builtin_amdgcn_sched_barrier(0);                                         \
    __builtin_amdgcn_s_setprio(1);                                             \
    _Pragma("unroll")                                                          \
    for (int nf = 0; nf < 4; ++nf) {                                           \
      acc[(MP)*2+0][nf] = __builtin_amdgcn_mfma_f32_16x16x32_bf16(             \
          a00, bn[nf][0], acc[(MP)*2+0][nf], 0, 0, 0);                         \
      acc[(MP)*2+1][nf] = __builtin_amdgcn_mfma_f32_16x16x32_bf16(             \
          a10, bn[nf][0], acc[(MP)*2+1][nf], 0, 0, 0);                         \
    }                                                                          \
    _Pragma("unroll")                                                          \
    for (int nf = 0; nf < 4; ++nf) {                                           \
      acc[(MP)*2+0][nf] = __builtin_amdgcn_mfma_f32_16x16x32_bf16(             \
          a01, bn[nf][1], acc[(MP)*2+0][nf], 0, 0, 0);                         \
      acc[(MP)*2+1][nf] = __builtin_amdgcn_mfma_f32_16x16x32_bf16(             \
          a11, bn[nf][1], acc[(MP)*2+1][nf], 0, 0, 0);                         \
    }                                                                          \
    __builtin_amdgcn_s_setprio(0);                                             \
    if (VM == 8)  asm volatile("s_waitcnt vmcnt(8)"  ::: "memory");            \
    if (VM == 10) asm volatile("s_waitcnt vmcnt(10)" ::: "memory");            \
    __builtin_amdgcn_s_barrier();                                              \
  }

  for (int bx = j0; bx * 256 < ne; bx += JSLOTS) {
    const u16* Tg = Tok + (size_t)(off + bx * 256) * KDIM + kbase;
    f32x4 acc[8][4] = {};
    s16x8 bn[4][2];

    // Prologue: 14 loads in exact FIFO order, then vmcnt(8)+barrier.
    STB(0, 0, 0); STB(0, 1, 0);       // Bq01 tile0
    STB(0, 2, 0); STB(0, 3, 0);       // Bq23 tile0
    STA(0, 0, 0); STA(0, 2, 0);       // Aq0,Aq2 tile0
    STA(0, 1, 0); STA(0, 3, 0);       // Aq1,Aq3 tile0
    STB(1, 0, 1); STB(1, 1, 1);       // Bq01 tile1
    STB(1, 2, 1); STB(1, 3, 1);       // Bq23 tile1
    STA(1, 0, 1); STA(1, 2, 1);       // Aq0,Aq2 tile1
    asm volatile("s_waitcnt vmcnt(8)" ::: "memory");
    __builtin_amdgcn_s_barrier();

    for (int j = 0; j < NITER; ++j) {
      int t1 = 2 * j + 1;
      int tc2 = (2 * j + 2 < NT) ? 2 * j + 2 : NT - 1;
      int tc3 = (2 * j + 3 < NT) ? 2 * j + 3 : NT - 1;
      PH(0, 0, 1,  0, 1, STA(1, 1, t1); STA(1, 3, t1));      // ph1
      PH(1, 0, 0, 10, 0, STB(0, 0, tc2); STB(0, 1, tc2));    // ph2
      PH(2, 0, 0,  0, 0, STB(0, 2, tc2); STB(0, 3, tc2));    // ph3
      PH(3, 0, 0,  8, 0, STA(0, 0, tc2); STA(0, 2, tc2));    // ph4
      PH(0, 1, 1,  0, 1, STA(0, 1, tc2); STA(0, 3, tc2));    // ph5
      PH(1, 1, 0, 10, 0, STB(1, 0, tc3); STB(1, 1, tc3));    // ph6
      PH(2, 1, 0,  0, 0, STB(1, 2, tc3); STB(1, 3, tc3));    // ph7
      PH(3, 1, 0,  8, 0, STA(1, 0, tc3); STA(1, 2, tc3));    // ph8
    }

    // epilogue: token = wt*64 + f*16 + lr (col), feature = wf*128 + r*16 + lg4 + j
#pragma unroll
    for (int f = 0; f < 4; ++f) {
      int tokl = bx * 256 + wt * 64 + f * 16 + lr;
      if (tokl >= ne) continue;
      size_t grow = (size_t)(off + tokl);
      if (EPI == 0) {
#pragma unroll
        for (int r = 0; r < 8; ++r) {
          ushort4 o;
          o.x = f2bf(gelu_fast(acc[r][f][0]));
          o.y = f2bf(gelu_fast(acc[r][f][1]));
          o.z = f2bf(gelu_fast(acc[r][f][2]));
          o.w = f2bf(gelu_fast(acc[r][f][3]));
          *(ushort4*)(Hout + grow * NOUT + panel * 256 + wf * 128 + r * 16 + lg4) = o;
        }
      } else {
        float w = pair_w[grow];
#pragma unroll
        for (int r = 0; r < 8; ++r) {
          float4 o;
          o.x = acc[r][f][0] * w; o.y = acc[r][f][1] * w;
          o.z = acc[r][f][2] * w; o.w = acc[r][f][3] * w;
          *(float4*)(Cpart + grow * NOUT + panel * 256 + wf * 128 + r * 16 + lg4) = o;
        }
      }
    }
  }
#undef PH
#undef STA
#undef STB
}

// ---------------------------------------------------------------------------
// Combine: out[token] = sum over 2 pairs x 2 K-parts
// ---------------------------------------------------------------------------
__global__ void combine(const float* __restrict__ pair_out, const int* __restrict__ pair_idx,
                        float* __restrict__ out) {
  const float* part1 = pair_out + (size_t)P_ * D_;
  int t = blockIdx.x;
  int p0 = pair_idx[t*2], p1 = pair_idx[t*2+1];
  int c = threadIdx.x * 4;
  float4 a0 = *(const float4*)(pair_out + (size_t)p0 * D_ + c);
  float4 a1 = *(const float4*)(part1    + (size_t)p0 * D_ + c);
  float4 b0 = *(const float4*)(pair_out + (size_t)p1 * D_ + c);
  float4 b1 = *(const float4*)(part1    + (size_t)p1 * D_ + c);
  float4 o;
  o.x = (a0.x + a1.x) + (b0.x + b1.x);
  o.y = (a0.y + a1.y) + (b0.y + b1.y);
  o.z = (a0.z + a1.z) + (b0.z + b1.z);
  o.w = (a0.w + a1.w) + (b0.w + b1.w);
  *(float4*)(out + (size_t)t * D_ + c) = o;
}

// ---------------------------------------------------------------------------
// Workspace layout (bytes):
//   w1b  [E][H][D] bf16 @ 0           (67108864)  <- aliased by pair_out parts
//   w2b  [E][D][H] bf16 @ 67108864    (67108864)
//   Xg   [PPAD][D] bf16 @ 134217728   (17301504)
//   Hb   [PPAD][H] bf16 @ 151519232   (69206016)
//   small buffers @ 220725248
//   pair_out: 2 parts x [P_][D_] f32 @ 0 (67108864, aliases dead w1b)
// ---------------------------------------------------------------------------
extern "C" void kernel_launch(void* const* d_in, const int* in_sizes, int n_in,
                              void* d_out, int out_size, void* d_ws, size_t ws_size,
                              hipStream_t stream) {
  const float* inputs      = (const float*)d_in[0];
  const float* task_param  = (const float*)d_in[1];
  const float* gate_img_w  = (const float*)d_in[2];
  const float* gate_img_b  = (const float*)d_in[3];
  const float* gate_txt_w  = (const float*)d_in[4];
  const float* gate_txt_b  = (const float*)d_in[5];
  const float* task_gate_w = (const float*)d_in[6];
  const float* task_gate_b = (const float*)d_in[7];
  const float* alpha       = (const float*)d_in[8];
  const float* w1          = (const float*)d_in[9];
  const float* w2          = (const float*)d_in[10];
  const int*   is_text     = (const int*)d_in[11];
  float* out = (float*)d_out;

  char* ws = (char*)d_ws;
  u16* w1b = (u16*)(ws + 0);
  u16* w2b = (u16*)(ws + 67108864);
  u16* Xg  = (u16*)(ws + 134217728);
  u16* Hb  = (u16*)(ws + 151519232);
  float4* sel_w   = (float4*)(ws + 220725248);
  float* pair_w   = (float*)(ws + 220725248 + 65536);
  int* pair_idx   = (int*)(ws + 220725248 + 98816);
  float* prob_part= (float*)(ws + 220725248 + 131584);
  int* count_part = (int*)(ws + 220725248 + 164352);
  int* counters   = (int*)(ws + 220725248 + 197120);
  float* pair_out = (float*)(ws + 0);  // 2 parts, aliases dead w1b

  int* counts  = counters;
  int* offs    = counters + 8;
  int* cursors = counters + 16;

  convtrans<D_, H_><<<dim3(H_/64, D_/64, E_), 256, 0, stream>>>(w1, w1b);
  convtrans<H_, D_><<<dim3(D_/64, H_/64, E_), 256, 0, stream>>>(w2, w2b);
  gating<<<dim3(T_/4), 256, 0, stream>>>(inputs, task_param, gate_img_w, gate_img_b,
      gate_txt_w, gate_txt_b, task_gate_w, task_gate_b, alpha, is_text,
      sel_w, prob_part, count_part);
  finalize<<<dim3(1), 256, 0, stream>>>(prob_part, count_part, counts, offs, cursors,
      out + (size_t)T_ * D_);
  scatter_gather<<<dim3(T_/4), 256, 0, stream>>>(inputs, sel_w, cursors, pair_w, pair_idx, Xg);
  // GEMM1: Tok=Xg, W=w1b; K=1024 (NT=16), 16 panels, 2 token-slots. 256 blocks.
  gemm256<0, D_, D_, H_, 16, 1, 2><<<dim3(256), 512, 0, stream>>>(
      Xg, w1b, counts, offs, pair_w, Hb, (float*)nullptr);
  // GEMM2: Tok=Hb, W=w2b; K=4096 split 2x2048 (NT=32), 4 panels, 4 token-slots. 256 blocks.
  gemm256<1, H_, H_/2, D_, 4, 2, 4><<<dim3(256), 512, 0, stream>>>(
      Hb, w2b, counts, offs, pair_w, (u16*)nullptr, pair_out);
  combine<<<dim3(T_), 256, 0, stream>>>(pair_out, pair_idx, out);
}